// Round 6
// baseline (358.956 us; speedup 1.0000x reference)
//
#include <hip/hip_runtime.h>
#include <stdint.h>

#define Bn 4
#define Sn 2048
#define Hn 1024
#define NHn 16
#define Mn 8192   // Bn*Sn

typedef unsigned short bf_t;
typedef __attribute__((ext_vector_type(8))) short s16x8;
typedef __attribute__((ext_vector_type(4))) short s16x4;
typedef __attribute__((ext_vector_type(8))) unsigned short u16x8;
typedef __attribute__((ext_vector_type(4))) unsigned short u16x4;
typedef __attribute__((ext_vector_type(4))) float f32x4;
typedef __attribute__((ext_vector_type(4))) unsigned int u32x4;
typedef __attribute__((ext_vector_type(2))) unsigned int u32x2;

__device__ __forceinline__ bf_t f2bf(float f) {
  unsigned int u = __float_as_uint(f);
  u += 0x7fffu + ((u >> 16) & 1u);   // RNE
  return (bf_t)(u >> 16);
}

// pack two f32 -> two bf16 (truncation) in one v_perm_b32
__device__ __forceinline__ unsigned pk2(float lo, float hi) {
  return __builtin_amdgcn_perm(__float_as_uint(hi), __float_as_uint(lo), 0x07060302u);
}
__device__ __forceinline__ s16x4 pack4(float a0, float a1, float a2, float a3) {
  u32x2 t;
  t[0] = pk2(a0, a1);
  t[1] = pk2(a2, a3);
  return __builtin_bit_cast(s16x4, t);
}

// K=16 bf16 MFMA: ISA v_mfma_f32_16x16x16_bf16; clang spelling "_1k" (v4i16 ops).
#define MFMA16K16(a, b, c) __builtin_amdgcn_mfma_f32_16x16x16bf16_1k(a, b, c, 0, 0, 0)
#define MFMA32(a, b, c) __builtin_amdgcn_mfma_f32_16x16x32_bf16(a, b, c, 0, 0, 0)

#define GLOAD16(gp, lp) __builtin_amdgcn_global_load_lds(              \
    (__attribute__((address_space(1))) void*)(gp),                     \
    (__attribute__((address_space(3))) void*)(lp), 16, 0, 0)

// ------- merged prep: 4 weight transposes + query fp32->bf16 convert -------
__global__ __launch_bounds__(256)
void prep(const float* __restrict__ Wq, const float* __restrict__ Wk,
          const float* __restrict__ Wv, const float* __restrict__ Wd,
          const float* __restrict__ query,
          bf_t* __restrict__ Wt, bf_t* __restrict__ Wdt, bf_t* __restrict__ Xb) {
  __shared__ float tile[32][33];
  const int z = blockIdx.z;
  const int tx = threadIdx.x;   // 0..31
  const int ty = threadIdx.y;   // 0..7
  if (z == 4) {
    const int bid = blockIdx.y * 32 + blockIdx.x;     // 0..1023
    const int t = ty * 32 + tx;
    const size_t base = (size_t)bid * 8192 + t * 4;
#pragma unroll
    for (int i = 0; i < 8; i++) {
      const f32x4 v = *(const f32x4*)(query + base + i * 1024);
      u16x4 o;
      o[0] = f2bf(v[0]); o[1] = f2bf(v[1]); o[2] = f2bf(v[2]); o[3] = f2bf(v[3]);
      *(u16x4*)(Xb + base + i * 1024) = o;
    }
    return;
  }
  const float* W = (z == 0) ? Wq : (z == 1) ? Wk : (z == 2) ? Wv : Wd;
  bf_t* dst = (z < 3) ? Wt + (size_t)z * Hn * Hn : Wdt;
  const int n0 = blockIdx.x * 32, k0 = blockIdx.y * 32;
#pragma unroll
  for (int i = 0; i < 4; i++)
    tile[ty + i * 8][tx] = W[(size_t)(k0 + ty + i * 8) * Hn + n0 + tx];
  __syncthreads();
#pragma unroll
  for (int i = 0; i < 4; i++) {
    const int nn = ty + i * 8, kk = tx;
    dst[(size_t)(n0 + nn) * Hn + k0 + kk] = f2bf(tile[kk][nn]);
  }
}

// -------- m97-style bf16 GEMM-BT, 128x128 tile, BK=32, dbuf LDS --------
__global__ __launch_bounds__(256, 3)
void gemm_bt(const bf_t* __restrict__ A, const bf_t* __restrict__ Bt,
             const float* __restrict__ b0, const float* __restrict__ b1,
             const float* __restrict__ b2, void* __restrict__ outp,
             int N, int K, int out_bf16)
{
  __shared__ bf_t As[2][4096];
  __shared__ bf_t Bs[2][4096];
  const int tid = threadIdx.x;
  const int wave = tid >> 6, lane = tid & 63;
  const int l15 = lane & 15, quad = lane >> 4;
  const int bm = blockIdx.y * 128, bn = blockIdx.x * 128;
  const int wm = (wave >> 1) * 64, wn = (wave & 1) * 64;
  const int srow = tid >> 2;          // 0..63
  const int scol = (tid & 3) * 8;     // 0..24

  const bf_t* Ag = A + (size_t)(bm + srow) * K + scol;
  const bf_t* Bg = Bt + (size_t)(bn + srow) * K + scol;

  f32x4 acc[4][4] = {};

  GLOAD16(Ag, As[0] + tid * 8);
  GLOAD16(Ag + (size_t)64 * K, As[0] + 2048 + tid * 8);
  GLOAD16(Bg, Bs[0] + tid * 8);
  GLOAD16(Bg + (size_t)64 * K, Bs[0] + 2048 + tid * 8);

  const int nIter = K >> 5;
  for (int i = 0; i < nIter; i++) {
    const int cur = i & 1;
    __syncthreads();
    if (i + 1 < nIter) {
      const int k0 = (i + 1) * 32;
      GLOAD16(Ag + k0, As[cur ^ 1] + tid * 8);
      GLOAD16(Ag + (size_t)64 * K + k0, As[cur ^ 1] + 2048 + tid * 8);
      GLOAD16(Bg + k0, Bs[cur ^ 1] + tid * 8);
      GLOAD16(Bg + (size_t)64 * K + k0, Bs[cur ^ 1] + 2048 + tid * 8);
    }
    s16x8 af[4], bfr[4];
#pragma unroll
    for (int mi = 0; mi < 4; mi++)
      af[mi] = *(const s16x8*)&As[cur][(wm + mi * 16 + l15) * 32 + quad * 8];
#pragma unroll
    for (int ni = 0; ni < 4; ni++)
      bfr[ni] = *(const s16x8*)&Bs[cur][(wn + ni * 16 + l15) * 32 + quad * 8];
#pragma unroll
    for (int mi = 0; mi < 4; mi++)
#pragma unroll
      for (int ni = 0; ni < 4; ni++)
        acc[mi][ni] = __builtin_amdgcn_mfma_f32_16x16x32_bf16(af[mi], bfr[ni], acc[mi][ni], 0, 0, 0);
  }

#pragma unroll
  for (int ni = 0; ni < 4; ni++) {
    const int gn = bn + wn + ni * 16 + l15;
    const float* bp = (gn < 1024) ? b0 : ((gn < 2048) ? b1 : b2);
    const float bias = bp[gn & 1023];
#pragma unroll
    for (int mi = 0; mi < 4; mi++) {
#pragma unroll
      for (int r = 0; r < 4; r++) {
        const int gm = bm + wm + mi * 16 + quad * 4 + r;
        const float v = acc[mi][ni][r] + bias;
        if (out_bf16) ((bf_t*)outp)[(size_t)gm * N + gn] = f2bf(v);
        else          ((float*)outp)[(size_t)gm * N + gn] = v;
      }
    }
  }
}

// -------- V swizzle (+ f = exp(mask) fold + Fb table) --------
__global__ __launch_bounds__(256)
void kvswz(const bf_t* __restrict__ qkv, bf_t* __restrict__ Vf,
           const float* __restrict__ mask, bf_t* __restrict__ Fb) {
  __shared__ unsigned int P32[64 * 33];   // [dv][k-pair], stride 33
  const int t = threadIdx.x;
  const int bh = blockIdx.y, b = bh >> 4, h = bh & 15;
  const int k0 = blockIdx.x * 64;

  {
    const int kp = t >> 3;           // 0..31 (k-pair)
    const int d0 = (t & 7) * 8;
    const int kg = k0 + 2 * kp;
    // f = exp(mask) = exp2(mask*log2e); exactly 1.0 for zero mask
    const float f0 = __builtin_amdgcn_exp2f(mask[b * Sn + kg] * 1.44269504f);
    const float f1 = __builtin_amdgcn_exp2f(mask[b * Sn + kg + 1] * 1.44269504f);
    const bf_t* p0 = qkv + (size_t)(b * Sn + kg) * 3072 + 2048 + h * 64 + d0;
    const u16x8 r0 = *(const u16x8*)p0;
    const u16x8 r1 = *(const u16x8*)(p0 + 3072);
#pragma unroll
    for (int j = 0; j < 8; j++) {
      const float v0 = __uint_as_float((unsigned)r0[j] << 16) * f0;
      const float v1 = __uint_as_float((unsigned)r1[j] << 16) * f1;
      // truncation pack: exact when f==1 (low mantissa bits already zero)
      P32[(d0 + j) * 33 + kp] = pk2(v0, v1);
    }
  }
  if (h == 0 && t < 64) {
    const float fm = __builtin_amdgcn_exp2f(mask[b * Sn + k0 + t] * 1.44269504f);
    Fb[b * Sn + k0 + t] = f2bf(fm);
  }
  __syncthreads();
  bf_t* dst0 = Vf + ((size_t)(bh * 32 + blockIdx.x) * 8) * 512;
#pragma unroll
  for (int i = 0; i < 2; i++) {
    const int p = t + i * 256;
    const int fp = p >> 6, lane = p & 63;
    const int dvblk = fp >> 1, kpair = fp & 1;
    const int l15 = lane & 15, quad = (lane >> 4) & 3;
    const int d = dvblk * 16 + l15;
    const int c = kpair * 16 + quad * 2;
    u32x4 w;
    w[0] = P32[d * 33 + c];
    w[1] = P32[d * 33 + c + 1];
    w[2] = P32[d * 33 + c + 8];
    w[3] = P32[d * 33 + c + 9];
    // kpair-major frag order so a 32-k chunk is contiguous (2048 el)
    *(u32x4*)(dst0 + (size_t)(kpair * 4 + dvblk) * 512 + lane * 8) = w;
  }
}

// ---- flash attention: qf=4 (64 q/wave) x k-split x2, 4-wave 256-thr blocks ----
// R5 post-mortem: qf=4 halves LDS-read traffic (the dominant pipe, ~46 us in
// R4) but R5's 512-block grid starved TLP (occ 22%). This keeps qf=4 and
// restores grid=1024 via 4-wave blocks: wv in {0,1} q-waves x g in {0,1}
// k-groups, 128 q-rows/block, 36 KB LDS -> 4 blocks/CU. K staged direct from
// QKV (R5-proven mapping; 2 frags/thread since staging group = 128 threads).
// Natural VGPR allocation (no min-waves cap — R2 lesson).
__global__ __launch_bounds__(256)
void attn(const bf_t* __restrict__ qkv, const bf_t* __restrict__ Vf,
          const bf_t* __restrict__ Fb, bf_t* __restrict__ ctx)
{
  __shared__ __align__(16) bf_t KV[2][2][2][2048];   // [g][K/V][buf][.] 32 KB
  __shared__ __align__(16) bf_t Fs[2048];            // 4 KB f-table

  const int tid = threadIdx.x;            // 0..255
  const int wave = tid >> 6, lane = tid & 63;
  const int g = wave >> 1, wv = wave & 1; // k-split group, q-wave in group
  const int tg = tid & 127;               // thread-in-staging-group (2 waves)
  const int l15 = lane & 15, quad = lane >> 4;
  const int idx = blockIdx.x;
  const int bh = idx & 63, b = bh >> 4, h = bh & 15;
  const int q0 = (idx >> 6) * 128;        // 128 q-rows per block

  // stage f-table (covered by first barrier's drain)
  GLOAD16(Fb + (size_t)b * Sn + tid * 8, Fs + tid * 8);

  // Q frags: 4 per wave (64 q-rows), x32 B-operand layout
  s16x8 aq[4][2];
#pragma unroll
  for (int qf = 0; qf < 4; qf++) {
    const bf_t* qp = qkv + (size_t)(b * Sn + q0 + wv * 64 + qf * 16 + l15) * 3072 + h * 64;
    aq[qf][0] = *(const s16x8*)(qp + quad * 8);
    aq[qf][1] = *(const s16x8*)(qp + 32 + quad * 8);
  }

  f32x4 lacc[4] = {};   // f-weighted row-sum via MFMA; cross-lane-complete
  f32x4 o[4][4] = {};   // O^T partial: [qf][dvblk]

  // K direct-from-QKV: thread tg stages frags (ks=0,halfs) and (ks=1,halfs)
  const int lane_s = tg & 63, l15s = lane_s & 15, quads = lane_s >> 4;
  const int halfs = tg >> 6;              // 0..1
  const bf_t* kq = qkv + (size_t)(b * Sn + g * 1024 + l15s) * 3072
                   + 1024 + h * 64 + halfs * 32 + quads * 8;
  const bf_t* vb = Vf + (size_t)bh * 131072 + (size_t)g * 65536;
  const float C1 = 0.125f * 1.44269504f;   // (1/sqrt(64)) * log2(e)

  // preload tile 0 of this group's k-half
  GLOAD16(kq,                KV[g][0][0] + tg * 8);
  GLOAD16(kq + 16 * 3072,    KV[g][0][0] + 1024 + tg * 8);
  GLOAD16(vb + tg * 8,        KV[g][1][0] + tg * 8);
  GLOAD16(vb + 1024 + tg * 8, KV[g][1][0] + 1024 + tg * 8);

  for (int it = 0; it < 32; ++it) {
    const int cur = it & 1;
    __syncthreads();   // waits prefetch of buf[cur] + prior reads of buf[cur^1]
    if (it < 31) {
      const bf_t* kn = kq + (size_t)(it + 1) * 98304;   // 32 rows * 3072
      GLOAD16(kn,             KV[g][0][cur ^ 1] + tg * 8);
      GLOAD16(kn + 16 * 3072, KV[g][0][cur ^ 1] + 1024 + tg * 8);
      const bf_t* vn = vb + (size_t)(it + 1) * 2048;
      GLOAD16(vn + tg * 8,        KV[g][1][cur ^ 1] + tg * 8);
      GLOAD16(vn + 1024 + tg * 8, KV[g][1][cur ^ 1] + 1024 + tg * 8);
    }

    // S^T = K·Q^T (x32) -> p = exp2(s*C1); l += f-weighted colsum (f-MFMA)
    s16x4 pb[4][2];
#pragma unroll
    for (int e = 0; e < 2; e++) {
      const s16x8 k0f = *(const s16x8*)&KV[g][0][cur][(e * 2 + 0) * 512 + lane * 8];
      const s16x8 k1f = *(const s16x8*)&KV[g][0][cur][(e * 2 + 1) * 512 + lane * 8];
      const s16x4 ff = *(const s16x4*)&Fs[g * 1024 + it * 32 + e * 16 + quad * 4];
#pragma unroll
      for (int qf = 0; qf < 4; qf++) {
        f32x4 acc = {};
        __builtin_amdgcn_s_setprio(1);
        acc = MFMA32(k0f, aq[qf][0], acc);
        acc = MFMA32(k1f, aq[qf][1], acc);
        __builtin_amdgcn_s_setprio(0);
        const float p0 = __builtin_amdgcn_exp2f(acc[0] * C1);
        const float p1 = __builtin_amdgcn_exp2f(acc[1] * C1);
        const float p2 = __builtin_amdgcn_exp2f(acc[2] * C1);
        const float p3 = __builtin_amdgcn_exp2f(acc[3] * C1);
        pb[qf][e] = pack4(p0, p1, p2, p3);
        lacc[qf] = MFMA16K16(ff, pb[qf][e], lacc[qf]);
      }
    }

    // O^T += V^T·P^T (x16, A = V frag, B = P register-direct)
    __builtin_amdgcn_s_setprio(1);
#pragma unroll
    for (int dvblk = 0; dvblk < 4; dvblk++) {
      const s16x8 vv = *(const s16x8*)&KV[g][1][cur][dvblk * 512 + lane * 8];
      const s16x4 vlo = {vv[0], vv[1], vv[2], vv[3]};
      const s16x4 vhi = {vv[4], vv[5], vv[6], vv[7]};
#pragma unroll
      for (int qf = 0; qf < 4; qf++) {
        o[qf][dvblk] = MFMA16K16(vlo, pb[qf][0], o[qf][dvblk]);
        o[qf][dvblk] = MFMA16K16(vhi, pb[qf][1], o[qf][dvblk]);
      }
    }
    __builtin_amdgcn_s_setprio(0);
  }

  // ---- cross-split merge via LDS, single pass (128 q x 64 dv = 32 KB) ----
  __syncthreads();
  float* sm = (float*)&KV[0][0][0][0];   // 32 KB scratch
  float* sl = (float*)&Fs[0];            // 128 f32 row-sums
  if (g == 1) {
#pragma unroll
    for (int qf = 0; qf < 4; qf++) {
      const int rp = wv * 64 + qf * 16 + l15;
#pragma unroll
      for (int dvblk = 0; dvblk < 4; dvblk++) {
        const int col = (dvblk * 16 + quad * 4 + l15 * 4) & 63;  // skew
        *(f32x4*)&sm[rp * 64 + col] = o[qf][dvblk];
      }
      if (quad == 0) sl[rp] = lacc[qf][0];
    }
  }
  __syncthreads();
  if (g == 0) {
#pragma unroll
    for (int qf = 0; qf < 4; qf++) {
      const int rp = wv * 64 + qf * 16 + l15;
      const float inv = 1.f / (lacc[qf][0] + sl[rp]);
      const size_t grow = (size_t)(b * Sn + q0 + rp);
#pragma unroll
      for (int dvblk = 0; dvblk < 4; dvblk++) {
        const int col = (dvblk * 16 + quad * 4 + l15 * 4) & 63;
        const f32x4 o2 = *(const f32x4*)&sm[rp * 64 + col];
        u16x4 ov;
#pragma unroll
        for (int r = 0; r < 4; r++) ov[r] = f2bf((o[qf][dvblk][r] + o2[r]) * inv);
        *(u16x4*)&ctx[grow * Hn + h * 64 + dvblk * 16 + quad * 4] = ov;
      }
    }
  }
}

// ---------------- LayerNorm + residual ----------------
__global__ __launch_bounds__(256)
void ln_res(const float* __restrict__ hid, const float* __restrict__ query,
            const float* __restrict__ gamma, const float* __restrict__ beta,
            float* __restrict__ out)
{
  const int row = blockIdx.x, t = threadIdx.x;
  const f32x4 h = *(const f32x4*)(hid + (size_t)row * Hn + t * 4);
  float s = h[0] + h[1] + h[2] + h[3];
  float ss = h[0]*h[0] + h[1]*h[1] + h[2]*h[2] + h[3]*h[3];
#pragma unroll
  for (int m = 32; m; m >>= 1) { s += __shfl_xor(s, m); ss += __shfl_xor(ss, m); }
  __shared__ float red[8];
  if ((t & 63) == 0) { red[t >> 6] = s; red[4 + (t >> 6)] = ss; }
  __syncthreads();
  s = red[0] + red[1] + red[2] + red[3];
  ss = red[4] + red[5] + red[6] + red[7];
  const float mu = s * (1.f / Hn);
  const float rs = rsqrtf(ss * (1.f / Hn) - mu * mu + 1e-12f);
  const f32x4 q = *(const f32x4*)(query + (size_t)row * Hn + t * 4);
  const f32x4 g = *(const f32x4*)(gamma + t * 4);
  const f32x4 be = *(const f32x4*)(beta + t * 4);
  f32x4 o;
#pragma unroll
  for (int j = 0; j < 4; j++) o[j] = (h[j] - mu) * rs * g[j] + be[j] + q[j];
  *(f32x4*)(out + (size_t)row * Hn + t * 4) = o;
}

extern "C" void kernel_launch(void* const* d_in, const int* in_sizes, int n_in,
                              void* d_out, int out_size, void* d_ws, size_t ws_size,
                              hipStream_t stream) {
  const float* query = (const float*)d_in[0];
  const float* mask  = (const float*)d_in[1];
  const float* Wq = (const float*)d_in[2];
  const float* bq = (const float*)d_in[3];
  const float* Wk = (const float*)d_in[4];
  const float* bk = (const float*)d_in[5];
  const float* Wv = (const float*)d_in[6];
  const float* bv = (const float*)d_in[7];
  const float* Wd = (const float*)d_in[8];
  const float* bd = (const float*)d_in[9];
  const float* gamma = (const float*)d_in[10];
  const float* beta  = (const float*)d_in[11];

  char* w = (char*)d_ws;
  bf_t* Xb  = (bf_t*)w;  w += (size_t)Mn * Hn * 2;        // 16 MB
  bf_t* Wt  = (bf_t*)w;  w += (size_t)3 * Hn * Hn * 2;    // 6 MB  (Wq^T|Wk^T|Wv^T)
  bf_t* Wdt = (bf_t*)w;  w += (size_t)Hn * Hn * 2;        // 2 MB
  bf_t* QKV = (bf_t*)w;  w += (size_t)Mn * 3 * Hn * 2;    // 48 MB
  bf_t* Vf  = (bf_t*)w;  w += (size_t)64 * 32 * 4096 * 2; // 16 MB
  bf_t* Ctx = (bf_t*)w;  w += (size_t)Mn * Hn * 2;        // 16 MB
  float* Hid = (float*)w;  w += (size_t)Mn * Hn * 4;       // 32 MB
  bf_t* Fb = (bf_t*)w;                                     // 16 KB (f = exp(mask) bf16)

  prep<<<dim3(32, 32, 5), dim3(32, 8), 0, stream>>>(Wq, Wk, Wv, Wd, query, Wt, Wdt, Xb);
  gemm_bt<<<dim3(24, 64), 256, 0, stream>>>(Xb, Wt, bq, bk, bv, QKV, 3072, 1024, 1);
  kvswz<<<dim3(32, 64), 256, 0, stream>>>(QKV, Vf, mask, Fb);
  attn<<<1024, 256, 0, stream>>>(QKV, Vf, Fb, Ctx);
  gemm_bt<<<dim3(8, 64), 256, 0, stream>>>(Ctx, Wdt, bd, bd, bd, Hid, 1024, 1024, 0);
  ln_res<<<Mn, 256, 0, stream>>>(Hid, query, gamma, beta, (float*)d_out);
}

// Round 7
// 329.756 us; speedup vs baseline: 1.0885x; 1.0885x over previous
//
#include <hip/hip_runtime.h>
#include <stdint.h>

#define Bn 4
#define Sn 2048
#define Hn 1024
#define NHn 16
#define Mn 8192   // Bn*Sn

typedef unsigned short bf_t;
typedef __attribute__((ext_vector_type(8))) short s16x8;
typedef __attribute__((ext_vector_type(4))) short s16x4;
typedef __attribute__((ext_vector_type(8))) unsigned short u16x8;
typedef __attribute__((ext_vector_type(4))) unsigned short u16x4;
typedef __attribute__((ext_vector_type(4))) float f32x4;
typedef __attribute__((ext_vector_type(4))) unsigned int u32x4;
typedef __attribute__((ext_vector_type(2))) unsigned int u32x2;

__device__ __forceinline__ bf_t f2bf(float f) {
  unsigned int u = __float_as_uint(f);
  u += 0x7fffu + ((u >> 16) & 1u);   // RNE
  return (bf_t)(u >> 16);
}

// pack two f32 -> two bf16 (truncation) in one v_perm_b32
__device__ __forceinline__ unsigned pk2(float lo, float hi) {
  return __builtin_amdgcn_perm(__float_as_uint(hi), __float_as_uint(lo), 0x07060302u);
}
__device__ __forceinline__ s16x4 pack4(float a0, float a1, float a2, float a3) {
  u32x2 t;
  t[0] = pk2(a0, a1);
  t[1] = pk2(a2, a3);
  return __builtin_bit_cast(s16x4, t);
}

// K=16 bf16 MFMA: ISA v_mfma_f32_16x16x16_bf16; clang spelling "_1k" (v4i16 ops).
#define MFMA16K16(a, b, c) __builtin_amdgcn_mfma_f32_16x16x16bf16_1k(a, b, c, 0, 0, 0)
#define MFMA32(a, b, c) __builtin_amdgcn_mfma_f32_16x16x32_bf16(a, b, c, 0, 0, 0)

#define GLOAD16(gp, lp) __builtin_amdgcn_global_load_lds(              \
    (__attribute__((address_space(1))) void*)(gp),                     \
    (__attribute__((address_space(3))) void*)(lp), 16, 0, 0)

// ------- merged prep: 4 weight transposes + query fp32->bf16 convert -------
__global__ __launch_bounds__(256)
void prep(const float* __restrict__ Wq, const float* __restrict__ Wk,
          const float* __restrict__ Wv, const float* __restrict__ Wd,
          const float* __restrict__ query,
          bf_t* __restrict__ Wt, bf_t* __restrict__ Wdt, bf_t* __restrict__ Xb) {
  __shared__ float tile[32][33];
  const int z = blockIdx.z;
  const int tx = threadIdx.x;   // 0..31
  const int ty = threadIdx.y;   // 0..7
  if (z == 4) {
    const int bid = blockIdx.y * 32 + blockIdx.x;     // 0..1023
    const int t = ty * 32 + tx;
    const size_t base = (size_t)bid * 8192 + t * 4;
#pragma unroll
    for (int i = 0; i < 8; i++) {
      const f32x4 v = *(const f32x4*)(query + base + i * 1024);
      u16x4 o;
      o[0] = f2bf(v[0]); o[1] = f2bf(v[1]); o[2] = f2bf(v[2]); o[3] = f2bf(v[3]);
      *(u16x4*)(Xb + base + i * 1024) = o;
    }
    return;
  }
  const float* W = (z == 0) ? Wq : (z == 1) ? Wk : (z == 2) ? Wv : Wd;
  bf_t* dst = (z < 3) ? Wt + (size_t)z * Hn * Hn : Wdt;
  const int n0 = blockIdx.x * 32, k0 = blockIdx.y * 32;
#pragma unroll
  for (int i = 0; i < 4; i++)
    tile[ty + i * 8][tx] = W[(size_t)(k0 + ty + i * 8) * Hn + n0 + tx];
  __syncthreads();
#pragma unroll
  for (int i = 0; i < 4; i++) {
    const int nn = ty + i * 8, kk = tx;
    dst[(size_t)(n0 + nn) * Hn + k0 + kk] = f2bf(tile[kk][nn]);
  }
}

// -------- m97-style bf16 GEMM-BT, 128x128 tile, BK=32, dbuf LDS --------
__global__ __launch_bounds__(256, 3)
void gemm_bt(const bf_t* __restrict__ A, const bf_t* __restrict__ Bt,
             const float* __restrict__ b0, const float* __restrict__ b1,
             const float* __restrict__ b2, void* __restrict__ outp,
             int N, int K, int out_bf16)
{
  __shared__ bf_t As[2][4096];
  __shared__ bf_t Bs[2][4096];
  const int tid = threadIdx.x;
  const int wave = tid >> 6, lane = tid & 63;
  const int l15 = lane & 15, quad = lane >> 4;
  const int bm = blockIdx.y * 128, bn = blockIdx.x * 128;
  const int wm = (wave >> 1) * 64, wn = (wave & 1) * 64;
  const int srow = tid >> 2;          // 0..63
  const int scol = (tid & 3) * 8;     // 0..24

  const bf_t* Ag = A + (size_t)(bm + srow) * K + scol;
  const bf_t* Bg = Bt + (size_t)(bn + srow) * K + scol;

  f32x4 acc[4][4] = {};

  GLOAD16(Ag, As[0] + tid * 8);
  GLOAD16(Ag + (size_t)64 * K, As[0] + 2048 + tid * 8);
  GLOAD16(Bg, Bs[0] + tid * 8);
  GLOAD16(Bg + (size_t)64 * K, Bs[0] + 2048 + tid * 8);

  const int nIter = K >> 5;
  for (int i = 0; i < nIter; i++) {
    const int cur = i & 1;
    __syncthreads();
    if (i + 1 < nIter) {
      const int k0 = (i + 1) * 32;
      GLOAD16(Ag + k0, As[cur ^ 1] + tid * 8);
      GLOAD16(Ag + (size_t)64 * K + k0, As[cur ^ 1] + 2048 + tid * 8);
      GLOAD16(Bg + k0, Bs[cur ^ 1] + tid * 8);
      GLOAD16(Bg + (size_t)64 * K + k0, Bs[cur ^ 1] + 2048 + tid * 8);
    }
    s16x8 af[4], bfr[4];
#pragma unroll
    for (int mi = 0; mi < 4; mi++)
      af[mi] = *(const s16x8*)&As[cur][(wm + mi * 16 + l15) * 32 + quad * 8];
#pragma unroll
    for (int ni = 0; ni < 4; ni++)
      bfr[ni] = *(const s16x8*)&Bs[cur][(wn + ni * 16 + l15) * 32 + quad * 8];
#pragma unroll
    for (int mi = 0; mi < 4; mi++)
#pragma unroll
      for (int ni = 0; ni < 4; ni++)
        acc[mi][ni] = __builtin_amdgcn_mfma_f32_16x16x32_bf16(af[mi], bfr[ni], acc[mi][ni], 0, 0, 0);
  }

#pragma unroll
  for (int ni = 0; ni < 4; ni++) {
    const int gn = bn + wn + ni * 16 + l15;
    const float* bp = (gn < 1024) ? b0 : ((gn < 2048) ? b1 : b2);
    const float bias = bp[gn & 1023];
#pragma unroll
    for (int mi = 0; mi < 4; mi++) {
#pragma unroll
      for (int r = 0; r < 4; r++) {
        const int gm = bm + wm + mi * 16 + quad * 4 + r;
        const float v = acc[mi][ni][r] + bias;
        if (out_bf16) ((bf_t*)outp)[(size_t)gm * N + gn] = f2bf(v);
        else          ((float*)outp)[(size_t)gm * N + gn] = v;
      }
    }
  }
}

// -------- V swizzle (+ f = exp(mask) fold + Fb table) --------
// K branch gone: attn stages K directly from QKV (byte-identical LDS image).
__global__ __launch_bounds__(256)
void kvswz(const bf_t* __restrict__ qkv, bf_t* __restrict__ Vf,
           const float* __restrict__ mask, bf_t* __restrict__ Fb) {
  __shared__ unsigned int P32[64 * 33];   // [dv][k-pair], stride 33
  const int t = threadIdx.x;
  const int bh = blockIdx.y, b = bh >> 4, h = bh & 15;
  const int k0 = blockIdx.x * 64;

  {
    const int kp = t >> 3;           // 0..31 (k-pair)
    const int d0 = (t & 7) * 8;
    const int kg = k0 + 2 * kp;
    // f = exp(mask) = exp2(mask*log2e); exactly 1.0 for zero mask
    const float f0 = __builtin_amdgcn_exp2f(mask[b * Sn + kg] * 1.44269504f);
    const float f1 = __builtin_amdgcn_exp2f(mask[b * Sn + kg + 1] * 1.44269504f);
    const bf_t* p0 = qkv + (size_t)(b * Sn + kg) * 3072 + 2048 + h * 64 + d0;
    const u16x8 r0 = *(const u16x8*)p0;
    const u16x8 r1 = *(const u16x8*)(p0 + 3072);
#pragma unroll
    for (int j = 0; j < 8; j++) {
      const float v0 = __uint_as_float((unsigned)r0[j] << 16) * f0;
      const float v1 = __uint_as_float((unsigned)r1[j] << 16) * f1;
      // truncation pack: exact when f==1 (low mantissa bits already zero)
      P32[(d0 + j) * 33 + kp] = pk2(v0, v1);
    }
  }
  if (h == 0 && t < 64) {
    const float fm = __builtin_amdgcn_exp2f(mask[b * Sn + k0 + t] * 1.44269504f);
    Fb[b * Sn + k0 + t] = f2bf(fm);
  }
  __syncthreads();
  bf_t* dst0 = Vf + ((size_t)(bh * 32 + blockIdx.x) * 8) * 512;
#pragma unroll
  for (int i = 0; i < 2; i++) {
    const int p = t + i * 256;
    const int fp = p >> 6, lane = p & 63;
    const int dvblk = fp >> 1, kpair = fp & 1;
    const int l15 = lane & 15, quad = (lane >> 4) & 3;
    const int d = dvblk * 16 + l15;
    const int c = kpair * 16 + quad * 2;
    u32x4 w;
    w[0] = P32[d * 33 + c];
    w[1] = P32[d * 33 + c + 1];
    w[2] = P32[d * 33 + c + 8];
    w[3] = P32[d * 33 + c + 9];
    // kpair-major frag order so a 32-k chunk is contiguous (2048 el)
    *(u32x4*)(dst0 + (size_t)(kpair * 4 + dvblk) * 512 + lane * 8) = w;
  }
}

// ---- flash attention: R4 geometry (proven 98 us) + direct-K staging ----
// 8 waves (4 q-waves x k-split 2), qf=2, k-tile 32, dbuf LDS, 36 KB ->
// 4 blocks/CU x 8 waves = 32 waves/CU. TLP is first-order (R4 vs R5/R6:
// 98 vs 125/135 us at 32 vs 16 waves/CU). K staged direct from QKV via
// per-lane-source global_load_lds (R5/R6-proven mapping, byte-identical
// image): frag=tg>>6 -> (ks,half); row=g*1024+it*32+ks*16+l15; col=
// half*32+quad*8. Deletes the Kf round-trip. Natural VGPR (no cap).
__global__ __launch_bounds__(512)
void attn(const bf_t* __restrict__ qkv, const bf_t* __restrict__ Vf,
          const bf_t* __restrict__ Fb, bf_t* __restrict__ ctx)
{
  __shared__ __align__(16) bf_t KV[2][2][2][2048];   // [g][K/V][buf][.] 32 KB
  __shared__ __align__(16) bf_t Fs[2048];            // 4 KB f-table

  const int tid = threadIdx.x;
  const int wave = tid >> 6, lane = tid & 63;
  const int g = wave >> 2, wv = wave & 3;            // k-split group, wave-in-group
  const int tg = tid & 255;                          // thread-in-group
  const int l15 = lane & 15, quad = lane >> 4;
  const int idx = blockIdx.x;
  const int bh = idx & 63, b = bh >> 4, h = bh & 15;
  const int q0 = (idx >> 6) * 128;

  // stage f-table (covered by first barrier's drain)
  if (tid < 256) GLOAD16(Fb + (size_t)b * Sn + tid * 8, Fs + tid * 8);

  // Q as x32 B-operand: lane&15 = q-row, d = quad*8+j. 2 q-frags per wave.
  s16x8 aq[2][2];
#pragma unroll
  for (int qf = 0; qf < 2; qf++) {
    const bf_t* qp = qkv + (size_t)(b * Sn + q0 + wv * 32 + qf * 16 + l15) * 3072 + h * 64;
    aq[qf][0] = *(const s16x8*)(qp + quad * 8);
    aq[qf][1] = *(const s16x8*)(qp + 32 + quad * 8);
  }

  f32x4 lacc[2] = {};   // f-weighted row-sum via MFMA; cross-lane-complete
  f32x4 o[2][4] = {};   // O^T partial: [qf][dvblk]

  // K direct-from-QKV: thread tg stages frag (ks,half), row l15s
  const int ksf = tg >> 7, kh = (tg >> 6) & 1;       // frag = ksf*2+kh
  const int lane_s = tg & 63, l15s = lane_s & 15, quads = lane_s >> 4;
  const bf_t* kq = qkv + (size_t)(b * Sn + g * 1024 + ksf * 16 + l15s) * 3072
                   + 1024 + h * 64 + kh * 32 + quads * 8;
  const bf_t* vb = Vf + (size_t)bh * 131072 + (size_t)g * 65536;
  const float C1 = 0.125f * 1.44269504f;   // (1/sqrt(64)) * log2(e)

  // preload tile 0 of this group's k-half
  GLOAD16(kq, KV[g][0][0] + tg * 8);
  GLOAD16(vb + tg * 8, KV[g][1][0] + tg * 8);

  for (int it = 0; it < 32; ++it) {
    const int cur = it & 1;
    __syncthreads();   // waits prefetch of buf[cur] + prior reads of buf[cur^1]
    if (it < 31) {
      GLOAD16(kq + (size_t)(it + 1) * 98304, KV[g][0][cur ^ 1] + tg * 8);  // 32 rows * 3072
      GLOAD16(vb + (it + 1) * 2048 + tg * 8, KV[g][1][cur ^ 1] + tg * 8);
    }

    // S^T = K·Q^T (x32) -> p = exp2(s*C1); l += f-weighted colsum (f-MFMA)
    s16x4 pb[2][2];
#pragma unroll
    for (int e = 0; e < 2; e++) {
      const s16x8 k0f = *(const s16x8*)&KV[g][0][cur][(e * 2 + 0) * 512 + lane * 8];
      const s16x8 k1f = *(const s16x8*)&KV[g][0][cur][(e * 2 + 1) * 512 + lane * 8];
      const s16x4 ff = *(const s16x4*)&Fs[g * 1024 + it * 32 + e * 16 + quad * 4];
#pragma unroll
      for (int qf = 0; qf < 2; qf++) {
        f32x4 acc = {};
        __builtin_amdgcn_s_setprio(1);
        acc = MFMA32(k0f, aq[qf][0], acc);
        acc = MFMA32(k1f, aq[qf][1], acc);
        __builtin_amdgcn_s_setprio(0);
        const float p0 = __builtin_amdgcn_exp2f(acc[0] * C1);
        const float p1 = __builtin_amdgcn_exp2f(acc[1] * C1);
        const float p2 = __builtin_amdgcn_exp2f(acc[2] * C1);
        const float p3 = __builtin_amdgcn_exp2f(acc[3] * C1);
        pb[qf][e] = pack4(p0, p1, p2, p3);
        lacc[qf] = MFMA16K16(ff, pb[qf][e], lacc[qf]);
      }
    }

    // O^T += V^T·P^T (x16, A = V frag, B = P register-direct)
    __builtin_amdgcn_s_setprio(1);
#pragma unroll
    for (int dvblk = 0; dvblk < 4; dvblk++) {
      const s16x8 vv = *(const s16x8*)&KV[g][1][cur][dvblk * 512 + lane * 8];
      const s16x4 vlo = {vv[0], vv[1], vv[2], vv[3]};
      const s16x4 vhi = {vv[4], vv[5], vv[6], vv[7]};
#pragma unroll
      for (int qf = 0; qf < 2; qf++) {
        o[qf][dvblk] = MFMA16K16(vlo, pb[qf][0], o[qf][dvblk]);
        o[qf][dvblk] = MFMA16K16(vhi, pb[qf][1], o[qf][dvblk]);
      }
    }
    __builtin_amdgcn_s_setprio(0);
  }

  // ---- cross-split merge via LDS (reuse K/V buffers as f32 scratch) ----
  __syncthreads();
  float* sm = (float*)&KV[0][0][0][0];   // 8192 f32 = 128 q x 64 dv
  float* sl = (float*)&Fs[0];            // 128 f32 row-sums
  if (g == 1) {
#pragma unroll
    for (int qf = 0; qf < 2; qf++) {
      const int row = wv * 32 + qf * 16 + l15;
#pragma unroll
      for (int dvblk = 0; dvblk < 4; dvblk++) {
        const int col = (dvblk * 16 + quad * 4 + l15 * 4) & 63;  // skew: 2-way max
        *(f32x4*)&sm[row * 64 + col] = o[qf][dvblk];
      }
      if (quad == 0) sl[row] = lacc[qf][0];
    }
  }
  __syncthreads();
  if (g == 0) {
#pragma unroll
    for (int qf = 0; qf < 2; qf++) {
      const int row = wv * 32 + qf * 16 + l15;
      const float inv = 1.f / (lacc[qf][0] + sl[row]);
      const size_t grow = (size_t)(b * Sn + q0 + row);
#pragma unroll
      for (int dvblk = 0; dvblk < 4; dvblk++) {
        const int col = (dvblk * 16 + quad * 4 + l15 * 4) & 63;
        const f32x4 o2 = *(const f32x4*)&sm[row * 64 + col];
        u16x4 ov;
#pragma unroll
        for (int r = 0; r < 4; r++) ov[r] = f2bf((o[qf][dvblk][r] + o2[r]) * inv);
        *(u16x4*)&ctx[grow * Hn + h * 64 + dvblk * 16 + quad * 4] = ov;
      }
    }
  }
}

// ---------------- LayerNorm + residual ----------------
__global__ __launch_bounds__(256)
void ln_res(const float* __restrict__ hid, const float* __restrict__ query,
            const float* __restrict__ gamma, const float* __restrict__ beta,
            float* __restrict__ out)
{
  const int row = blockIdx.x, t = threadIdx.x;
  const f32x4 h = *(const f32x4*)(hid + (size_t)row * Hn + t * 4);
  float s = h[0] + h[1] + h[2] + h[3];
  float ss = h[0]*h[0] + h[1]*h[1] + h[2]*h[2] + h[3]*h[3];
#pragma unroll
  for (int m = 32; m; m >>= 1) { s += __shfl_xor(s, m); ss += __shfl_xor(ss, m); }
  __shared__ float red[8];
  if ((t & 63) == 0) { red[t >> 6] = s; red[4 + (t >> 6)] = ss; }
  __syncthreads();
  s = red[0] + red[1] + red[2] + red[3];
  ss = red[4] + red[5] + red[6] + red[7];
  const float mu = s * (1.f / Hn);
  const float rs = rsqrtf(ss * (1.f / Hn) - mu * mu + 1e-12f);
  const f32x4 q = *(const f32x4*)(query + (size_t)row * Hn + t * 4);
  const f32x4 g = *(const f32x4*)(gamma + t * 4);
  const f32x4 be = *(const f32x4*)(beta + t * 4);
  f32x4 o;
#pragma unroll
  for (int j = 0; j < 4; j++) o[j] = (h[j] - mu) * rs * g[j] + be[j] + q[j];
  *(f32x4*)(out + (size_t)row * Hn + t * 4) = o;
}

extern "C" void kernel_launch(void* const* d_in, const int* in_sizes, int n_in,
                              void* d_out, int out_size, void* d_ws, size_t ws_size,
                              hipStream_t stream) {
  const float* query = (const float*)d_in[0];
  const float* mask  = (const float*)d_in[1];
  const float* Wq = (const float*)d_in[2];
  const float* bq = (const float*)d_in[3];
  const float* Wk = (const float*)d_in[4];
  const float* bk = (const float*)d_in[5];
  const float* Wv = (const float*)d_in[6];
  const float* bv = (const float*)d_in[7];
  const float* Wd = (const float*)d_in[8];
  const float* bd = (const float*)d_in[9];
  const float* gamma = (const float*)d_in[10];
  const float* beta  = (const float*)d_in[11];

  char* w = (char*)d_ws;
  bf_t* Xb  = (bf_t*)w;  w += (size_t)Mn * Hn * 2;        // 16 MB
  bf_t* Wt  = (bf_t*)w;  w += (size_t)3 * Hn * Hn * 2;    // 6 MB  (Wq^T|Wk^T|Wv^T)
  bf_t* Wdt = (bf_t*)w;  w += (size_t)Hn * Hn * 2;        // 2 MB
  bf_t* QKV = (bf_t*)w;  w += (size_t)Mn * 3 * Hn * 2;    // 48 MB
  bf_t* Vf  = (bf_t*)w;  w += (size_t)64 * 32 * 4096 * 2; // 16 MB
  bf_t* Ctx = (bf_t*)w;  w += (size_t)Mn * Hn * 2;        // 16 MB
  float* Hid = (float*)w;  w += (size_t)Mn * Hn * 4;       // 32 MB
  bf_t* Fb = (bf_t*)w;                                     // 16 KB (f = exp(mask) bf16)

  prep<<<dim3(32, 32, 5), dim3(32, 8), 0, stream>>>(Wq, Wk, Wv, Wd, query, Wt, Wdt, Xb);
  gemm_bt<<<dim3(24, 64), 256, 0, stream>>>(Xb, Wt, bq, bk, bv, QKV, 3072, 1024, 1);
  kvswz<<<dim3(32, 64), 256, 0, stream>>>(QKV, Vf, mask, Fb);
  attn<<<1024, 512, 0, stream>>>(QKV, Vf, Fb, Ctx);
  gemm_bt<<<dim3(8, 64), 256, 0, stream>>>(Ctx, Wdt, bd, bd, bd, Hid, 1024, 1024, 0);
  ln_res<<<Mn, 256, 0, stream>>>(Hid, query, gamma, beta, (float*)d_out);
}

// Round 8
// 328.842 us; speedup vs baseline: 1.0916x; 1.0028x over previous
//
#include <hip/hip_runtime.h>
#include <stdint.h>

#define Bn 4
#define Sn 2048
#define Hn 1024
#define NHn 16
#define Mn 8192   // Bn*Sn

typedef unsigned short bf_t;
typedef __attribute__((ext_vector_type(8))) short s16x8;
typedef __attribute__((ext_vector_type(4))) short s16x4;
typedef __attribute__((ext_vector_type(8))) unsigned short u16x8;
typedef __attribute__((ext_vector_type(4))) unsigned short u16x4;
typedef __attribute__((ext_vector_type(4))) float f32x4;
typedef __attribute__((ext_vector_type(4))) unsigned int u32x4;
typedef __attribute__((ext_vector_type(2))) unsigned int u32x2;

__device__ __forceinline__ bf_t f2bf(float f) {
  unsigned int u = __float_as_uint(f);
  u += 0x7fffu + ((u >> 16) & 1u);   // RNE
  return (bf_t)(u >> 16);
}

// pack two f32 -> two bf16 (truncation) in one v_perm_b32
__device__ __forceinline__ unsigned pk2(float lo, float hi) {
  return __builtin_amdgcn_perm(__float_as_uint(hi), __float_as_uint(lo), 0x07060302u);
}
__device__ __forceinline__ s16x4 pack4(float a0, float a1, float a2, float a3) {
  u32x2 t;
  t[0] = pk2(a0, a1);
  t[1] = pk2(a2, a3);
  return __builtin_bit_cast(s16x4, t);
}

// K=16 bf16 MFMA: ISA v_mfma_f32_16x16x16_bf16; clang spelling "_1k" (v4i16 ops).
#define MFMA16K16(a, b, c) __builtin_amdgcn_mfma_f32_16x16x16bf16_1k(a, b, c, 0, 0, 0)
#define MFMA32(a, b, c) __builtin_amdgcn_mfma_f32_16x16x32_bf16(a, b, c, 0, 0, 0)

#define GLOAD16(gp, lp) __builtin_amdgcn_global_load_lds(              \
    (__attribute__((address_space(1))) void*)(gp),                     \
    (__attribute__((address_space(3))) void*)(lp), 16, 0, 0)

// ------- merged prep: 4 weight transposes + query fp32->bf16 convert -------
__global__ __launch_bounds__(256)
void prep(const float* __restrict__ Wq, const float* __restrict__ Wk,
          const float* __restrict__ Wv, const float* __restrict__ Wd,
          const float* __restrict__ query,
          bf_t* __restrict__ Wt, bf_t* __restrict__ Wdt, bf_t* __restrict__ Xb) {
  __shared__ float tile[32][33];
  const int z = blockIdx.z;
  const int tx = threadIdx.x;   // 0..31
  const int ty = threadIdx.y;   // 0..7
  if (z == 4) {
    const int bid = blockIdx.y * 32 + blockIdx.x;     // 0..1023
    const int t = ty * 32 + tx;
    const size_t base = (size_t)bid * 8192 + t * 4;
#pragma unroll
    for (int i = 0; i < 8; i++) {
      const f32x4 v = *(const f32x4*)(query + base + i * 1024);
      u16x4 o;
      o[0] = f2bf(v[0]); o[1] = f2bf(v[1]); o[2] = f2bf(v[2]); o[3] = f2bf(v[3]);
      *(u16x4*)(Xb + base + i * 1024) = o;
    }
    return;
  }
  const float* W = (z == 0) ? Wq : (z == 1) ? Wk : (z == 2) ? Wv : Wd;
  bf_t* dst = (z < 3) ? Wt + (size_t)z * Hn * Hn : Wdt;
  const int n0 = blockIdx.x * 32, k0 = blockIdx.y * 32;
#pragma unroll
  for (int i = 0; i < 4; i++)
    tile[ty + i * 8][tx] = W[(size_t)(k0 + ty + i * 8) * Hn + n0 + tx];
  __syncthreads();
#pragma unroll
  for (int i = 0; i < 4; i++) {
    const int nn = ty + i * 8, kk = tx;
    dst[(size_t)(n0 + nn) * Hn + k0 + kk] = f2bf(tile[kk][nn]);
  }
}

// -------- m97-style bf16 GEMM-BT, 128x128 tile, BK=32, dbuf LDS --------
// + T1 XCD-aware block swizzle (bijective: both grids divisible by 8):
// blocks on the same XCD get consecutive linear tiles -> A row-panel is
// read once into that XCD's L2 instead of once per XCD.
__global__ __launch_bounds__(256, 3)
void gemm_bt(const bf_t* __restrict__ A, const bf_t* __restrict__ Bt,
             const float* __restrict__ b0, const float* __restrict__ b1,
             const float* __restrict__ b2, void* __restrict__ outp,
             int N, int K, int out_bf16)
{
  __shared__ bf_t As[2][4096];
  __shared__ bf_t Bs[2][4096];
  const int tid = threadIdx.x;
  const int wave = tid >> 6, lane = tid & 63;
  const int l15 = lane & 15, quad = lane >> 4;

  const int nwg = gridDim.x * gridDim.y;
  const int lin = blockIdx.y * gridDim.x + blockIdx.x;
  const int qc = nwg >> 3;                       // nwg % 8 == 0 (1536 / 512)
  const int wg = (lin & 7) * qc + (lin >> 3);    // bijective XCD chunking
  const int bxs = wg % gridDim.x, bys = wg / gridDim.x;
  const int bm = bys * 128, bn = bxs * 128;

  const int wm = (wave >> 1) * 64, wn = (wave & 1) * 64;
  const int srow = tid >> 2;          // 0..63
  const int scol = (tid & 3) * 8;     // 0..24

  const bf_t* Ag = A + (size_t)(bm + srow) * K + scol;
  const bf_t* Bg = Bt + (size_t)(bn + srow) * K + scol;

  f32x4 acc[4][4] = {};

  GLOAD16(Ag, As[0] + tid * 8);
  GLOAD16(Ag + (size_t)64 * K, As[0] + 2048 + tid * 8);
  GLOAD16(Bg, Bs[0] + tid * 8);
  GLOAD16(Bg + (size_t)64 * K, Bs[0] + 2048 + tid * 8);

  const int nIter = K >> 5;
  for (int i = 0; i < nIter; i++) {
    const int cur = i & 1;
    __syncthreads();
    if (i + 1 < nIter) {
      const int k0 = (i + 1) * 32;
      GLOAD16(Ag + k0, As[cur ^ 1] + tid * 8);
      GLOAD16(Ag + (size_t)64 * K + k0, As[cur ^ 1] + 2048 + tid * 8);
      GLOAD16(Bg + k0, Bs[cur ^ 1] + tid * 8);
      GLOAD16(Bg + (size_t)64 * K + k0, Bs[cur ^ 1] + 2048 + tid * 8);
    }
    s16x8 af[4], bfr[4];
#pragma unroll
    for (int mi = 0; mi < 4; mi++)
      af[mi] = *(const s16x8*)&As[cur][(wm + mi * 16 + l15) * 32 + quad * 8];
#pragma unroll
    for (int ni = 0; ni < 4; ni++)
      bfr[ni] = *(const s16x8*)&Bs[cur][(wn + ni * 16 + l15) * 32 + quad * 8];
#pragma unroll
    for (int mi = 0; mi < 4; mi++)
#pragma unroll
      for (int ni = 0; ni < 4; ni++)
        acc[mi][ni] = __builtin_amdgcn_mfma_f32_16x16x32_bf16(af[mi], bfr[ni], acc[mi][ni], 0, 0, 0);
  }

#pragma unroll
  for (int ni = 0; ni < 4; ni++) {
    const int gn = bn + wn + ni * 16 + l15;
    const float* bp = (gn < 1024) ? b0 : ((gn < 2048) ? b1 : b2);
    const float bias = bp[gn & 1023];
#pragma unroll
    for (int mi = 0; mi < 4; mi++) {
#pragma unroll
      for (int r = 0; r < 4; r++) {
        const int gm = bm + wm + mi * 16 + quad * 4 + r;
        const float v = acc[mi][ni][r] + bias;
        if (out_bf16) ((bf_t*)outp)[(size_t)gm * N + gn] = f2bf(v);
        else          ((float*)outp)[(size_t)gm * N + gn] = v;
      }
    }
  }
}

// -------- merged K/V swizzle (+ f = exp(mask) fold) in one launch --------
// R4-proven version: K staged to Kf (contiguous 1-KB-chunk reads in attn
// beat R7's 64-B-scattered direct-QKV staging by ~8 us).
__global__ __launch_bounds__(256)
void kvswz(const bf_t* __restrict__ qkv, bf_t* __restrict__ Kf,
           bf_t* __restrict__ Vf, const float* __restrict__ mask,
           bf_t* __restrict__ Fb) {
  __shared__ u32x4 smbuf[640];   // 10240 B, 16-aligned; overlaid per branch
  const int t = threadIdx.x;
  const int bh = blockIdx.y, b = bh >> 4, h = bh & 15;
  const int k0 = blockIdx.x * 64;

  if (blockIdx.z == 0) {
    bf_t* KT = (bf_t*)smbuf;   // stride 80 el = 160 B
#pragma unroll
    for (int i = 0; i < 2; i++) {
      const int c = t + i * 256;
      const int row = c >> 3, col8 = (c & 7) * 8;
      const u16x8 v = *(const u16x8*)(qkv + (size_t)(b * Sn + k0 + row) * 3072 + 1024 + h * 64 + col8);
      *(u16x8*)&KT[row * 80 + col8] = v;
    }
    __syncthreads();
    bf_t* dst0 = Kf + ((size_t)(bh * 32 + blockIdx.x) * 8) * 512;
#pragma unroll
    for (int i = 0; i < 2; i++) {
      const int p = t + i * 256;
      const int frag = p >> 6, lane = p & 63;
      const int ks = frag >> 1, half = frag & 1;
      const int l15 = lane & 15, quad = lane >> 4;
      const u16x8 v = *(const u16x8*)&KT[(ks * 16 + l15) * 80 + half * 32 + quad * 8];
      *(u16x8*)(dst0 + (size_t)frag * 512 + lane * 8) = v;
    }
  } else {
    unsigned int* P32 = (unsigned int*)smbuf;   // [dv][k-pair], stride 33
    {
      const int kp = t >> 3;           // 0..31 (k-pair)
      const int d0 = (t & 7) * 8;
      const int kg = k0 + 2 * kp;
      // f = exp(mask) = exp2(mask*log2e); exactly 1.0 for zero mask
      const float f0 = __builtin_amdgcn_exp2f(mask[b * Sn + kg] * 1.44269504f);
      const float f1 = __builtin_amdgcn_exp2f(mask[b * Sn + kg + 1] * 1.44269504f);
      const bf_t* p0 = qkv + (size_t)(b * Sn + kg) * 3072 + 2048 + h * 64 + d0;
      const u16x8 r0 = *(const u16x8*)p0;
      const u16x8 r1 = *(const u16x8*)(p0 + 3072);
#pragma unroll
      for (int j = 0; j < 8; j++) {
        const float v0 = __uint_as_float((unsigned)r0[j] << 16) * f0;
        const float v1 = __uint_as_float((unsigned)r1[j] << 16) * f1;
        // truncation pack: exact when f==1 (low mantissa bits already zero)
        P32[(d0 + j) * 33 + kp] = pk2(v0, v1);
      }
    }
    if (h == 0 && t < 64) {
      const float fm = __builtin_amdgcn_exp2f(mask[b * Sn + k0 + t] * 1.44269504f);
      Fb[b * Sn + k0 + t] = f2bf(fm);
    }
    __syncthreads();
    bf_t* dst0 = Vf + ((size_t)(bh * 32 + blockIdx.x) * 8) * 512;
#pragma unroll
    for (int i = 0; i < 2; i++) {
      const int p = t + i * 256;
      const int fp = p >> 6, lane = p & 63;
      const int dvblk = fp >> 1, kpair = fp & 1;
      const int l15 = lane & 15, quad = (lane >> 4) & 3;
      const int d = dvblk * 16 + l15;
      const int c = kpair * 16 + quad * 2;
      u32x4 w;
      w[0] = P32[d * 33 + c];
      w[1] = P32[d * 33 + c + 1];
      w[2] = P32[d * 33 + c + 8];
      w[3] = P32[d * 33 + c + 9];
      // kpair-major frag order so a 32-k chunk is contiguous (2048 el)
      *(u32x4*)(dst0 + (size_t)(kpair * 4 + dvblk) * 512 + lane * 8) = w;
    }
  }
}

// ---- flash attention: q-tile 256, 16 waves (8 q-waves x k-split 2) ----
// R7 analysis: attn sustains ~4.8 TB/s from L2/L3 on K/V re-reads (512 MB
// total; FETCH only 41 MB) with no pipe >50% -> L3-BW-bound. This geometry
// halves global K/V traffic (8 q-blocks per (b,h) instead of 16) while
// KEEPING 32 waves/CU: 512 blocks x 1024 thr = exactly 2 blocks/CU (2048
// thr, 72 KB LDS — both exact fits). Same per-wave body as R4 (proven 98 us,
// VGPR 48): qf=2, k-tile 32, dbuf, Kf/Vf contiguous staging. Merge epilogue
// in 2 passes of 128 rows (32 KB scratch).
__global__ __launch_bounds__(1024)
void attn(const bf_t* __restrict__ qkv, const bf_t* __restrict__ Kf,
          const bf_t* __restrict__ Vf, const bf_t* __restrict__ Fb,
          bf_t* __restrict__ ctx)
{
  __shared__ __align__(16) bf_t KV[2][2][2][2048];   // [g][K/V][buf][.] 32 KB
  __shared__ __align__(16) bf_t Fs[2048];            // 4 KB f-table

  const int tid = threadIdx.x;            // 0..1023
  const int wave = tid >> 6, lane = tid & 63;
  const int g = wave >> 3, wv = wave & 7; // k-split group, q-wave in group
  const int tg = tid & 511;               // thread-in-group
  const int l15 = lane & 15, quad = lane >> 4;
  const int idx = blockIdx.x;
  const int bh = idx & 63, b = bh >> 4, h = bh & 15;
  const int q0 = (idx >> 6) * 256;        // 256 q-rows per block

  // stage f-table (covered by first barrier's drain)
  if (tid < 256) GLOAD16(Fb + (size_t)b * Sn + tid * 8, Fs + tid * 8);

  // Q as x32 B-operand: lane&15 = q-row, d = quad*8+j. 2 q-frags per wave.
  s16x8 aq[2][2];
#pragma unroll
  for (int qf = 0; qf < 2; qf++) {
    const bf_t* qp = qkv + (size_t)(b * Sn + q0 + wv * 32 + qf * 16 + l15) * 3072 + h * 64;
    aq[qf][0] = *(const s16x8*)(qp + quad * 8);
    aq[qf][1] = *(const s16x8*)(qp + 32 + quad * 8);
  }

  f32x4 lacc[2] = {};   // f-weighted row-sum via MFMA; cross-lane-complete
  f32x4 o[2][4] = {};   // O^T partial: [qf][dvblk]

  const bf_t* kb = Kf + (size_t)bh * 131072 + (size_t)g * 65536;
  const bf_t* vb = Vf + (size_t)bh * 131072 + (size_t)g * 65536;
  const float C1 = 0.125f * 1.44269504f;   // (1/sqrt(64)) * log2(e)

  // preload tile 0: waves 0-3 of the group stage K, waves 4-7 stage V
  if (tg < 256) GLOAD16(kb + tg * 8, KV[g][0][0] + tg * 8);
  else          GLOAD16(vb + (tg - 256) * 8, KV[g][1][0] + (tg - 256) * 8);

  for (int it = 0; it < 32; ++it) {
    const int cur = it & 1;
    __syncthreads();   // waits prefetch of buf[cur] + prior reads of buf[cur^1]
    if (it < 31) {
      if (tg < 256)
        GLOAD16(kb + (it + 1) * 2048 + tg * 8, KV[g][0][cur ^ 1] + tg * 8);
      else
        GLOAD16(vb + (it + 1) * 2048 + (tg - 256) * 8, KV[g][1][cur ^ 1] + (tg - 256) * 8);
    }

    // S^T = K·Q^T (x32) -> p = exp2(s*C1); l += f-weighted colsum (f-MFMA)
    s16x4 pb[2][2];
#pragma unroll
    for (int e = 0; e < 2; e++) {
      const s16x8 k0f = *(const s16x8*)&KV[g][0][cur][(e * 2 + 0) * 512 + lane * 8];
      const s16x8 k1f = *(const s16x8*)&KV[g][0][cur][(e * 2 + 1) * 512 + lane * 8];
      const s16x4 ff = *(const s16x4*)&Fs[g * 1024 + it * 32 + e * 16 + quad * 4];
#pragma unroll
      for (int qf = 0; qf < 2; qf++) {
        f32x4 acc = {};
        __builtin_amdgcn_s_setprio(1);
        acc = MFMA32(k0f, aq[qf][0], acc);
        acc = MFMA32(k1f, aq[qf][1], acc);
        __builtin_amdgcn_s_setprio(0);
        const float p0 = __builtin_amdgcn_exp2f(acc[0] * C1);
        const float p1 = __builtin_amdgcn_exp2f(acc[1] * C1);
        const float p2 = __builtin_amdgcn_exp2f(acc[2] * C1);
        const float p3 = __builtin_amdgcn_exp2f(acc[3] * C1);
        pb[qf][e] = pack4(p0, p1, p2, p3);
        lacc[qf] = MFMA16K16(ff, pb[qf][e], lacc[qf]);
      }
    }

    // O^T += V^T·P^T (x16, A = V frag, B = P register-direct)
    __builtin_amdgcn_s_setprio(1);
#pragma unroll
    for (int dvblk = 0; dvblk < 4; dvblk++) {
      const s16x8 vv = *(const s16x8*)&KV[g][1][cur][dvblk * 512 + lane * 8];
      const s16x4 vlo = {vv[0], vv[1], vv[2], vv[3]};
      const s16x4 vhi = {vv[4], vv[5], vv[6], vv[7]};
#pragma unroll
      for (int qf = 0; qf < 2; qf++) {
        o[qf][dvblk] = MFMA16K16(vlo, pb[qf][0], o[qf][dvblk]);
        o[qf][dvblk] = MFMA16K16(vhi, pb[qf][1], o[qf][dvblk]);
      }
    }
    __builtin_amdgcn_s_setprio(0);
  }

  // ---- cross-split merge via LDS, 2 passes of 128 rows (32 KB scratch) ----
  float* sm = (float*)&KV[0][0][0][0];   // 128 q x 64 dv f32 = 32 KB
  float* sl = (float*)&Fs[0];            // 128 f32 row-sums
#pragma unroll
  for (int ph = 0; ph < 2; ph++) {
    __syncthreads();
    if (g == 1 && (wv >> 2) == ph) {
#pragma unroll
      for (int qf = 0; qf < 2; qf++) {
        const int rp = (wv & 3) * 32 + qf * 16 + l15;
#pragma unroll
        for (int dvblk = 0; dvblk < 4; dvblk++) {
          const int col = (dvblk * 16 + quad * 4 + l15 * 4) & 63;  // skew
          *(f32x4*)&sm[rp * 64 + col] = o[qf][dvblk];
        }
        if (quad == 0) sl[rp] = lacc[qf][0];
      }
    }
    __syncthreads();
    if (g == 0 && (wv >> 2) == ph) {
#pragma unroll
      for (int qf = 0; qf < 2; qf++) {
        const int rp = (wv & 3) * 32 + qf * 16 + l15;
        const float inv = 1.f / (lacc[qf][0] + sl[rp]);
        const size_t grow = (size_t)(b * Sn + q0 + wv * 32 + qf * 16 + l15);
#pragma unroll
        for (int dvblk = 0; dvblk < 4; dvblk++) {
          const int col = (dvblk * 16 + quad * 4 + l15 * 4) & 63;
          const f32x4 o2 = *(const f32x4*)&sm[rp * 64 + col];
          u16x4 ov;
#pragma unroll
          for (int r = 0; r < 4; r++) ov[r] = f2bf((o[qf][dvblk][r] + o2[r]) * inv);
          *(u16x4*)&ctx[grow * Hn + h * 64 + dvblk * 16 + quad * 4] = ov;
        }
      }
    }
  }
}

// ---------------- LayerNorm + residual ----------------
__global__ __launch_bounds__(256)
void ln_res(const float* __restrict__ hid, const float* __restrict__ query,
            const float* __restrict__ gamma, const float* __restrict__ beta,
            float* __restrict__ out)
{
  const int row = blockIdx.x, t = threadIdx.x;
  const f32x4 h = *(const f32x4*)(hid + (size_t)row * Hn + t * 4);
  float s = h[0] + h[1] + h[2] + h[3];
  float ss = h[0]*h[0] + h[1]*h[1] + h[2]*h[2] + h[3]*h[3];
#pragma unroll
  for (int m = 32; m; m >>= 1) { s += __shfl_xor(s, m); ss += __shfl_xor(ss, m); }
  __shared__ float red[8];
  if ((t & 63) == 0) { red[t >> 6] = s; red[4 + (t >> 6)] = ss; }
  __syncthreads();
  s = red[0] + red[1] + red[2] + red[3];
  ss = red[4] + red[5] + red[6] + red[7];
  const float mu = s * (1.f / Hn);
  const float rs = rsqrtf(ss * (1.f / Hn) - mu * mu + 1e-12f);
  const f32x4 q = *(const f32x4*)(query + (size_t)row * Hn + t * 4);
  const f32x4 g = *(const f32x4*)(gamma + t * 4);
  const f32x4 be = *(const f32x4*)(beta + t * 4);
  f32x4 o;
#pragma unroll
  for (int j = 0; j < 4; j++) o[j] = (h[j] - mu) * rs * g[j] + be[j] + q[j];
  *(f32x4*)(out + (size_t)row * Hn + t * 4) = o;
}

extern "C" void kernel_launch(void* const* d_in, const int* in_sizes, int n_in,
                              void* d_out, int out_size, void* d_ws, size_t ws_size,
                              hipStream_t stream) {
  const float* query = (const float*)d_in[0];
  const float* mask  = (const float*)d_in[1];
  const float* Wq = (const float*)d_in[2];
  const float* bq = (const float*)d_in[3];
  const float* Wk = (const float*)d_in[4];
  const float* bk = (const float*)d_in[5];
  const float* Wv = (const float*)d_in[6];
  const float* bv = (const float*)d_in[7];
  const float* Wd = (const float*)d_in[8];
  const float* bd = (const float*)d_in[9];
  const float* gamma = (const float*)d_in[10];
  const float* beta  = (const float*)d_in[11];

  char* w = (char*)d_ws;
  bf_t* Xb  = (bf_t*)w;  w += (size_t)Mn * Hn * 2;        // 16 MB
  bf_t* Wt  = (bf_t*)w;  w += (size_t)3 * Hn * Hn * 2;    // 6 MB  (Wq^T|Wk^T|Wv^T)
  bf_t* Wdt = (bf_t*)w;  w += (size_t)Hn * Hn * 2;        // 2 MB
  bf_t* QKV = (bf_t*)w;  w += (size_t)Mn * 3 * Hn * 2;    // 48 MB
  bf_t* Vf  = (bf_t*)w;  w += (size_t)64 * 32 * 4096 * 2; // 16 MB
  bf_t* Ctx = (bf_t*)w;  w += (size_t)Mn * Hn * 2;        // 16 MB
  // Kf aliases the Hid region: Kf consumed by attn before out-gemm writes Hid
  bf_t* Kf  = (bf_t*)w;                                    // 16 MB (within Hid's 32 MB)
  float* Hid = (float*)w;  w += (size_t)Mn * Hn * 4;       // 32 MB
  bf_t* Fb = (bf_t*)w;                                     // 16 KB (f = exp(mask) bf16)

  prep<<<dim3(32, 32, 5), dim3(32, 8), 0, stream>>>(Wq, Wk, Wv, Wd, query, Wt, Wdt, Xb);
  gemm_bt<<<dim3(24, 64), 256, 0, stream>>>(Xb, Wt, bq, bk, bv, QKV, 3072, 1024, 1);
  kvswz<<<dim3(32, 64, 2), 256, 0, stream>>>(QKV, Kf, Vf, mask, Fb);
  attn<<<512, 1024, 0, stream>>>(QKV, Kf, Vf, Fb, Ctx);
  gemm_bt<<<dim3(8, 64), 256, 0, stream>>>(Ctx, Wdt, bd, bd, bd, Hid, 1024, 1024, 0);
  ln_res<<<Mn, 256, 0, stream>>>(Hid, query, gamma, beta, (float*)d_out);
}

// Round 9
// 307.353 us; speedup vs baseline: 1.1679x; 1.0699x over previous
//
#include <hip/hip_runtime.h>
#include <stdint.h>

#define Bn 4
#define Sn 2048
#define Hn 1024
#define NHn 16
#define Mn 8192   // Bn*Sn

typedef unsigned short bf_t;
typedef __attribute__((ext_vector_type(8))) short s16x8;
typedef __attribute__((ext_vector_type(4))) short s16x4;
typedef __attribute__((ext_vector_type(8))) unsigned short u16x8;
typedef __attribute__((ext_vector_type(4))) unsigned short u16x4;
typedef __attribute__((ext_vector_type(4))) float f32x4;
typedef __attribute__((ext_vector_type(4))) unsigned int u32x4;
typedef __attribute__((ext_vector_type(2))) unsigned int u32x2;

__device__ __forceinline__ bf_t f2bf(float f) {
  unsigned int u = __float_as_uint(f);
  u += 0x7fffu + ((u >> 16) & 1u);   // RNE
  return (bf_t)(u >> 16);
}

// pack two f32 -> two bf16 (truncation) in one v_perm_b32
__device__ __forceinline__ unsigned pk2(float lo, float hi) {
  return __builtin_amdgcn_perm(__float_as_uint(hi), __float_as_uint(lo), 0x07060302u);
}
__device__ __forceinline__ s16x4 pack4(float a0, float a1, float a2, float a3) {
  u32x2 t;
  t[0] = pk2(a0, a1);
  t[1] = pk2(a2, a3);
  return __builtin_bit_cast(s16x4, t);
}

// K=16 bf16 MFMA: ISA v_mfma_f32_16x16x16_bf16; clang spelling "_1k" (v4i16 ops).
#define MFMA16K16(a, b, c) __builtin_amdgcn_mfma_f32_16x16x16bf16_1k(a, b, c, 0, 0, 0)
#define MFMA32(a, b, c) __builtin_amdgcn_mfma_f32_16x16x32_bf16(a, b, c, 0, 0, 0)

#define GLOAD16(gp, lp) __builtin_amdgcn_global_load_lds(              \
    (__attribute__((address_space(1))) void*)(gp),                     \
    (__attribute__((address_space(3))) void*)(lp), 16, 0, 0)

// ------- merged prep: 4 weight transposes + query fp32->bf16 + Fb table -------
__global__ __launch_bounds__(256)
void prep(const float* __restrict__ Wq, const float* __restrict__ Wk,
          const float* __restrict__ Wv, const float* __restrict__ Wd,
          const float* __restrict__ query, const float* __restrict__ mask,
          bf_t* __restrict__ Wt, bf_t* __restrict__ Wdt, bf_t* __restrict__ Xb,
          bf_t* __restrict__ Fb) {
  __shared__ float tile[32][33];
  const int z = blockIdx.z;
  const int tx = threadIdx.x;   // 0..31
  const int ty = threadIdx.y;   // 0..7
  if (z == 4) {
    const int bid = blockIdx.y * 32 + blockIdx.x;     // 0..1023
    const int t = ty * 32 + tx;
    const size_t base = (size_t)bid * 8192 + t * 4;
#pragma unroll
    for (int i = 0; i < 8; i++) {
      const f32x4 v = *(const f32x4*)(query + base + i * 1024);
      u16x4 o;
      o[0] = f2bf(v[0]); o[1] = f2bf(v[1]); o[2] = f2bf(v[2]); o[3] = f2bf(v[3]);
      *(u16x4*)(Xb + base + i * 1024) = o;
    }
    // Fb = f2bf(exp(mask)) for batch bid (blocks 0..3)
    if (bid < 4) {
#pragma unroll
      for (int i = 0; i < 8; i++) {
        const int s = t * 8 + i;
        Fb[bid * Sn + s] = f2bf(__builtin_amdgcn_exp2f(mask[(size_t)bid * Sn + s] * 1.44269504f));
      }
    }
    return;
  }
  const float* W = (z == 0) ? Wq : (z == 1) ? Wk : (z == 2) ? Wv : Wd;
  bf_t* dst = (z < 3) ? Wt + (size_t)z * Hn * Hn : Wdt;
  const int n0 = blockIdx.x * 32, k0 = blockIdx.y * 32;
#pragma unroll
  for (int i = 0; i < 4; i++)
    tile[ty + i * 8][tx] = W[(size_t)(k0 + ty + i * 8) * Hn + n0 + tx];
  __syncthreads();
#pragma unroll
  for (int i = 0; i < 4; i++) {
    const int nn = ty + i * 8, kk = tx;
    dst[(size_t)(n0 + nn) * Hn + k0 + kk] = f2bf(tile[kk][nn]);
  }
}

// -------- m97-style bf16 GEMM-BT, 128x128 tile, BK=32, dbuf LDS --------
// + T1 XCD swizzle. + fused K/V epilogue (fuse_kv): K-range blocks scatter
// straight into Kf's fragment layout; V-range blocks do the kvswz pair-pack
// transpose in LDS then emit u32x4 into Vf (f=exp(mask) folded, bit-exact
// replication of the old QKV->kvswz path). Deletes the kvswz launch.
__global__ __launch_bounds__(256, 3)
void gemm_bt(const bf_t* __restrict__ A, const bf_t* __restrict__ Bt,
             const float* __restrict__ b0, const float* __restrict__ b1,
             const float* __restrict__ b2, void* __restrict__ outp,
             int N, int K, int out_bf16,
             const float* __restrict__ mask, bf_t* __restrict__ Kf,
             bf_t* __restrict__ Vf, int fuse_kv)
{
  __shared__ __align__(16) char smem[33536];   // As|Bs (32KB) / VP (33.3KB epi)
  bf_t (*As)[4096] = (bf_t(*)[4096])smem;
  bf_t (*Bs)[4096] = (bf_t(*)[4096])(smem + 16384);

  const int tid = threadIdx.x;
  const int wave = tid >> 6, lane = tid & 63;
  const int l15 = lane & 15, quad = lane >> 4;

  const int nwg = gridDim.x * gridDim.y;
  const int lin = blockIdx.y * gridDim.x + blockIdx.x;
  const int qc = nwg >> 3;                       // nwg % 8 == 0 (1536 / 512)
  const int wg = (lin & 7) * qc + (lin >> 3);    // bijective XCD chunking
  const int bxs = wg % gridDim.x, bys = wg / gridDim.x;
  const int bm = bys * 128, bn = bxs * 128;

  const int wm = (wave >> 1) * 64, wn = (wave & 1) * 64;
  const int srow = tid >> 2;          // 0..63
  const int scol = (tid & 3) * 8;     // 0..24

  const bf_t* Ag = A + (size_t)(bm + srow) * K + scol;
  const bf_t* Bg = Bt + (size_t)(bn + srow) * K + scol;

  f32x4 acc[4][4] = {};

  GLOAD16(Ag, As[0] + tid * 8);
  GLOAD16(Ag + (size_t)64 * K, As[0] + 2048 + tid * 8);
  GLOAD16(Bg, Bs[0] + tid * 8);
  GLOAD16(Bg + (size_t)64 * K, Bs[0] + 2048 + tid * 8);

  const int nIter = K >> 5;
  for (int i = 0; i < nIter; i++) {
    const int cur = i & 1;
    __syncthreads();
    if (i + 1 < nIter) {
      const int k0 = (i + 1) * 32;
      GLOAD16(Ag + k0, As[cur ^ 1] + tid * 8);
      GLOAD16(Ag + (size_t)64 * K + k0, As[cur ^ 1] + 2048 + tid * 8);
      GLOAD16(Bg + k0, Bs[cur ^ 1] + tid * 8);
      GLOAD16(Bg + (size_t)64 * K + k0, Bs[cur ^ 1] + 2048 + tid * 8);
    }
    s16x8 af[4], bfr[4];
#pragma unroll
    for (int mi = 0; mi < 4; mi++)
      af[mi] = *(const s16x8*)&As[cur][(wm + mi * 16 + l15) * 32 + quad * 8];
#pragma unroll
    for (int ni = 0; ni < 4; ni++)
      bfr[ni] = *(const s16x8*)&Bs[cur][(wn + ni * 16 + l15) * 32 + quad * 8];
#pragma unroll
    for (int mi = 0; mi < 4; mi++)
#pragma unroll
      for (int ni = 0; ni < 4; ni++)
        acc[mi][ni] = __builtin_amdgcn_mfma_f32_16x16x32_bf16(af[mi], bfr[ni], acc[mi][ni], 0, 0, 0);
  }

  if (!fuse_kv || bn < 1024) {
    // ---- plain epilogue (Q range writes QKV; gemm2 writes Hid f32) ----
#pragma unroll
    for (int ni = 0; ni < 4; ni++) {
      const int gn = bn + wn + ni * 16 + l15;
      const float* bp = (gn < 1024) ? b0 : ((gn < 2048) ? b1 : b2);
      const float bias = bp[gn & 1023];
#pragma unroll
      for (int mi = 0; mi < 4; mi++) {
#pragma unroll
        for (int r = 0; r < 4; r++) {
          const int gm = bm + wm + mi * 16 + quad * 4 + r;
          const float v = acc[mi][ni][r] + bias;
          if (out_bf16) ((bf_t*)outp)[(size_t)gm * N + gn] = f2bf(v);
          else          ((float*)outp)[(size_t)gm * N + gn] = v;
        }
      }
    }
  } else if (bn < 2048) {
    // ---- K range: scatter into Kf fragment layout ----
    // Kf elem: [((bh*32+chunk)*8 + ks*2+half)*512 + (qo*16+l15o)*8 + j]
    // value = K[b, k=chunk*64+ks*16+l15o, h, d=half*32+qo*8+j]
    const int bb = bm >> 11, k0b = bm & 2047;
#pragma unroll
    for (int ni = 0; ni < 4; ni++) {
      const int dK = (bn - 1024) + wn + ni * 16 + l15;   // 0..1023
      const int h = dK >> 6, d = dK & 63;
      const float bias = b1[dK];
      const int half = d >> 5, qo = (d >> 3) & 3, j = d & 7;
      const size_t hb = (size_t)((bb * 16 + h) * 32) * 8 * 512;
#pragma unroll
      for (int mi = 0; mi < 4; mi++) {
#pragma unroll
        for (int r = 0; r < 4; r++) {
          const int kk = k0b + wm + mi * 16 + quad * 4 + r;
          const int chunk = kk >> 6, ks = (kk >> 4) & 3, l15o = kk & 15;
          Kf[hb + ((size_t)chunk * 8 + ks * 2 + half) * 512 + (qo * 16 + l15o) * 8 + j]
            = f2bf(acc[mi][ni][r] + bias);
        }
      }
    }
  } else {
    // ---- V range: kvswz pair-pack transpose in LDS, then u32x4 emission ----
    __syncthreads();   // all waves done reading As/Bs before VP overwrite
    unsigned* VP = (unsigned*)smem;   // [lc 0..127][kp 0..63] stride 65
    const int bb = bm >> 11, k0b = bm & 2047;
    float fv[4][4];
#pragma unroll
    for (int mi = 0; mi < 4; mi++)
#pragma unroll
      for (int r = 0; r < 4; r++) {
        const int kk = k0b + wm + mi * 16 + quad * 4 + r;
        fv[mi][r] = __builtin_amdgcn_exp2f(mask[(size_t)bb * Sn + kk] * 1.44269504f);
      }
#pragma unroll
    for (int ni = 0; ni < 4; ni++) {
      const int lc = wn + ni * 16 + l15;              // block-local col 0..127
      const float bias = b2[(bn - 2048) + lc];
#pragma unroll
      for (int mi = 0; mi < 4; mi++) {
#pragma unroll
        for (int rp = 0; rp < 2; rp++) {
          const int lr = wm + mi * 16 + quad * 4 + rp * 2;   // even k local
          const float v0 = __uint_as_float((unsigned)f2bf(acc[mi][ni][rp * 2]     + bias) << 16) * fv[mi][rp * 2];
          const float v1 = __uint_as_float((unsigned)f2bf(acc[mi][ni][rp * 2 + 1] + bias) << 16) * fv[mi][rp * 2 + 1];
          VP[lc * 65 + (lr >> 1)] = pk2(v0, v1);
        }
      }
    }
    __syncthreads();
    const int hbase = (bn - 2048) >> 6;   // 2 heads per block
#pragma unroll
    for (int i = 0; i < 8; i++) {
      const int p = tid + i * 256;        // 0..2047
      const int unit = p >> 9, fp = (p >> 6) & 7, ln2 = p & 63;
      const int uh = unit & 1, uc = unit >> 1;
      const int kpair = fp >> 2, dvb = fp & 3;
      const int l15o = ln2 & 15, qo = ln2 >> 4;
      const int lc = uh * 64 + dvb * 16 + l15o;
      const int kp = uc * 32 + kpair * 16 + qo * 2;
      u32x4 w;
      w[0] = VP[lc * 65 + kp];     w[1] = VP[lc * 65 + kp + 1];
      w[2] = VP[lc * 65 + kp + 8]; w[3] = VP[lc * 65 + kp + 9];
      const int bh = bb * 16 + hbase + uh, chunk = (k0b >> 6) + uc;
      *(u32x4*)(Vf + ((size_t)(bh * 32 + chunk) * 8 + fp) * 512 + ln2 * 8) = w;
    }
  }
}

// ---- flash attention: R4 geometry (proven 98 us): 8 waves, qf=2,
// k-split x2, k-tile 32, dbuf LDS, Kf/Vf contiguous staging, f-MFMA l. ----
__global__ __launch_bounds__(512)
void attn(const bf_t* __restrict__ qkv, const bf_t* __restrict__ Kf,
          const bf_t* __restrict__ Vf, const bf_t* __restrict__ Fb,
          bf_t* __restrict__ ctx)
{
  __shared__ __align__(16) bf_t KV[2][2][2][2048];   // [g][K/V][buf][.] 32 KB
  __shared__ __align__(16) bf_t Fs[2048];            // 4 KB f-table

  const int tid = threadIdx.x;
  const int wave = tid >> 6, lane = tid & 63;
  const int g = wave >> 2, wv = wave & 3;            // k-split group, wave-in-group
  const int tg = tid & 255;                          // thread-in-group
  const int l15 = lane & 15, quad = lane >> 4;
  const int idx = blockIdx.x;
  const int bh = idx & 63, b = bh >> 4, h = bh & 15;
  const int q0 = (idx >> 6) * 128;

  if (tid < 256) GLOAD16(Fb + (size_t)b * Sn + tid * 8, Fs + tid * 8);

  s16x8 aq[2][2];
#pragma unroll
  for (int qf = 0; qf < 2; qf++) {
    const bf_t* qp = qkv + (size_t)(b * Sn + q0 + wv * 32 + qf * 16 + l15) * 3072 + h * 64;
    aq[qf][0] = *(const s16x8*)(qp + quad * 8);
    aq[qf][1] = *(const s16x8*)(qp + 32 + quad * 8);
  }

  f32x4 lacc[2] = {};
  f32x4 o[2][4] = {};

  const bf_t* kb = Kf + (size_t)bh * 131072 + (size_t)g * 65536;
  const bf_t* vb = Vf + (size_t)bh * 131072 + (size_t)g * 65536;
  const float C1 = 0.125f * 1.44269504f;   // (1/sqrt(64)) * log2(e)

  GLOAD16(kb + tg * 8, KV[g][0][0] + tg * 8);
  GLOAD16(vb + tg * 8, KV[g][1][0] + tg * 8);

  for (int it = 0; it < 32; ++it) {
    const int cur = it & 1;
    __syncthreads();
    if (it < 31) {
      GLOAD16(kb + (it + 1) * 2048 + tg * 8, KV[g][0][cur ^ 1] + tg * 8);
      GLOAD16(vb + (it + 1) * 2048 + tg * 8, KV[g][1][cur ^ 1] + tg * 8);
    }

    s16x4 pb[2][2];
#pragma unroll
    for (int e = 0; e < 2; e++) {
      const s16x8 k0f = *(const s16x8*)&KV[g][0][cur][(e * 2 + 0) * 512 + lane * 8];
      const s16x8 k1f = *(const s16x8*)&KV[g][0][cur][(e * 2 + 1) * 512 + lane * 8];
      const s16x4 ff = *(const s16x4*)&Fs[g * 1024 + it * 32 + e * 16 + quad * 4];
#pragma unroll
      for (int qf = 0; qf < 2; qf++) {
        f32x4 acc = {};
        __builtin_amdgcn_s_setprio(1);
        acc = MFMA32(k0f, aq[qf][0], acc);
        acc = MFMA32(k1f, aq[qf][1], acc);
        __builtin_amdgcn_s_setprio(0);
        const float p0 = __builtin_amdgcn_exp2f(acc[0] * C1);
        const float p1 = __builtin_amdgcn_exp2f(acc[1] * C1);
        const float p2 = __builtin_amdgcn_exp2f(acc[2] * C1);
        const float p3 = __builtin_amdgcn_exp2f(acc[3] * C1);
        pb[qf][e] = pack4(p0, p1, p2, p3);
        lacc[qf] = MFMA16K16(ff, pb[qf][e], lacc[qf]);
      }
    }

    __builtin_amdgcn_s_setprio(1);
#pragma unroll
    for (int dvblk = 0; dvblk < 4; dvblk++) {
      const s16x8 vv = *(const s16x8*)&KV[g][1][cur][dvblk * 512 + lane * 8];
      const s16x4 vlo = {vv[0], vv[1], vv[2], vv[3]};
      const s16x4 vhi = {vv[4], vv[5], vv[6], vv[7]};
#pragma unroll
      for (int qf = 0; qf < 2; qf++) {
        o[qf][dvblk] = MFMA16K16(vlo, pb[qf][0], o[qf][dvblk]);
        o[qf][dvblk] = MFMA16K16(vhi, pb[qf][1], o[qf][dvblk]);
      }
    }
    __builtin_amdgcn_s_setprio(0);
  }

  // ---- cross-split merge via LDS ----
  __syncthreads();
  float* sm = (float*)&KV[0][0][0][0];   // 128 q x 64 dv
  float* sl = (float*)&Fs[0];            // 128 row-sums
  if (g == 1) {
#pragma unroll
    for (int qf = 0; qf < 2; qf++) {
      const int row = wv * 32 + qf * 16 + l15;
#pragma unroll
      for (int dvblk = 0; dvblk < 4; dvblk++) {
        const int col = (dvblk * 16 + quad * 4 + l15 * 4) & 63;  // skew
        *(f32x4*)&sm[row * 64 + col] = o[qf][dvblk];
      }
      if (quad == 0) sl[row] = lacc[qf][0];
    }
  }
  __syncthreads();
  if (g == 0) {
#pragma unroll
    for (int qf = 0; qf < 2; qf++) {
      const int row = wv * 32 + qf * 16 + l15;
      const float inv = 1.f / (lacc[qf][0] + sl[row]);
      const size_t grow = (size_t)(b * Sn + q0 + row);
#pragma unroll
      for (int dvblk = 0; dvblk < 4; dvblk++) {
        const int col = (dvblk * 16 + quad * 4 + l15 * 4) & 63;
        const f32x4 o2 = *(const f32x4*)&sm[row * 64 + col];
        u16x4 ov;
#pragma unroll
        for (int r = 0; r < 4; r++) ov[r] = f2bf((o[qf][dvblk][r] + o2[r]) * inv);
        *(u16x4*)&ctx[grow * Hn + h * 64 + dvblk * 16 + quad * 4] = ov;
      }
    }
  }
}

// ---------------- LayerNorm + residual ----------------
__global__ __launch_bounds__(256)
void ln_res(const float* __restrict__ hid, const float* __restrict__ query,
            const float* __restrict__ gamma, const float* __restrict__ beta,
            float* __restrict__ out)
{
  const int row = blockIdx.x, t = threadIdx.x;
  const f32x4 h = *(const f32x4*)(hid + (size_t)row * Hn + t * 4);
  float s = h[0] + h[1] + h[2] + h[3];
  float ss = h[0]*h[0] + h[1]*h[1] + h[2]*h[2] + h[3]*h[3];
#pragma unroll
  for (int m = 32; m; m >>= 1) { s += __shfl_xor(s, m); ss += __shfl_xor(ss, m); }
  __shared__ float red[8];
  if ((t & 63) == 0) { red[t >> 6] = s; red[4 + (t >> 6)] = ss; }
  __syncthreads();
  s = red[0] + red[1] + red[2] + red[3];
  ss = red[4] + red[5] + red[6] + red[7];
  const float mu = s * (1.f / Hn);
  const float rs = rsqrtf(ss * (1.f / Hn) - mu * mu + 1e-12f);
  const f32x4 q = *(const f32x4*)(query + (size_t)row * Hn + t * 4);
  const f32x4 g = *(const f32x4*)(gamma + t * 4);
  const f32x4 be = *(const f32x4*)(beta + t * 4);
  f32x4 o;
#pragma unroll
  for (int j = 0; j < 4; j++) o[j] = (h[j] - mu) * rs * g[j] + be[j] + q[j];
  *(f32x4*)(out + (size_t)row * Hn + t * 4) = o;
}

extern "C" void kernel_launch(void* const* d_in, const int* in_sizes, int n_in,
                              void* d_out, int out_size, void* d_ws, size_t ws_size,
                              hipStream_t stream) {
  const float* query = (const float*)d_in[0];
  const float* mask  = (const float*)d_in[1];
  const float* Wq = (const float*)d_in[2];
  const float* bq = (const float*)d_in[3];
  const float* Wk = (const float*)d_in[4];
  const float* bk = (const float*)d_in[5];
  const float* Wv = (const float*)d_in[6];
  const float* bv = (const float*)d_in[7];
  const float* Wd = (const float*)d_in[8];
  const float* bd = (const float*)d_in[9];
  const float* gamma = (const float*)d_in[10];
  const float* beta  = (const float*)d_in[11];

  char* w = (char*)d_ws;
  bf_t* Xb  = (bf_t*)w;  w += (size_t)Mn * Hn * 2;        // 16 MB
  bf_t* Wt  = (bf_t*)w;  w += (size_t)3 * Hn * Hn * 2;    // 6 MB  (Wq^T|Wk^T|Wv^T)
  bf_t* Wdt = (bf_t*)w;  w += (size_t)Hn * Hn * 2;        // 2 MB
  bf_t* QKV = (bf_t*)w;  w += (size_t)Mn * 3 * Hn * 2;    // 48 MB (Q third used)
  bf_t* Vf  = (bf_t*)w;  w += (size_t)64 * 32 * 4096 * 2; // 16 MB
  bf_t* Ctx = (bf_t*)w;  w += (size_t)Mn * Hn * 2;        // 16 MB
  // Kf aliases the Hid region: Kf consumed by attn before out-gemm writes Hid
  bf_t* Kf  = (bf_t*)w;                                    // 16 MB (within Hid's 32 MB)
  float* Hid = (float*)w;  w += (size_t)Mn * Hn * 4;       // 32 MB
  bf_t* Fb = (bf_t*)w;                                     // 16 KB (f = exp(mask) bf16)

  prep<<<dim3(32, 32, 5), dim3(32, 8), 0, stream>>>(Wq, Wk, Wv, Wd, query, mask, Wt, Wdt, Xb, Fb);
  gemm_bt<<<dim3(24, 64), 256, 0, stream>>>(Xb, Wt, bq, bk, bv, QKV, 3072, 1024, 1,
                                            mask, Kf, Vf, 1);
  attn<<<1024, 512, 0, stream>>>(QKV, Kf, Vf, Fb, Ctx);
  gemm_bt<<<dim3(8, 64), 256, 0, stream>>>(Ctx, Wdt, bd, bd, bd, Hid, 1024, 1024, 0,
                                           nullptr, nullptr, nullptr, 0);
  ln_res<<<Mn, 256, 0, stream>>>(Hid, query, gamma, beta, (float*)d_out);
}